// Round 8
// baseline (1017.194 us; speedup 1.0000x reference)
//
#include <hip/hip_runtime.h>
#include <hip/hip_fp16.h>
#include <math.h>

#define D1 128
#define NEG 0.2f
#define NODE_SHIFT 9
#define BIN_NODES 512
#define MAXBIN 256

typedef _Float16 v8h __attribute__((ext_vector_type(8)));
typedef float v4f __attribute__((ext_vector_type(4)));

__device__ __forceinline__ float elu_f(float v){ return v > 0.f ? v : __expf(v) - 1.f; }

__device__ __forceinline__ unsigned f2h2(float a, float b){           // a->low, b->high
    return ((unsigned)__half_as_ushort(__float2half_rn(b)) << 16) |
           (unsigned)__half_as_ushort(__float2half_rn(a));
}
__device__ __forceinline__ float2 h2f2(unsigned u){
    float lo = __half2float(__ushort_as_half((unsigned short)(u & 0xffffu)));
    float hi = __half2float(__ushort_as_half((unsigned short)(u >> 16)));
    return make_float2(lo, hi);
}

// ---------------- binned CSR build ----------------
// staged entry: (dstLow << 17) | src   (src < 2^17, dstLow < 2^9)

__global__ __launch_bounds__(256) void kb_hist(const int* __restrict__ ei,
                                               int* __restrict__ binCnt,
                                               int n_edges, int etot, int nbin){
    __shared__ int h[MAXBIN];
    for (int i = threadIdx.x; i < nbin; i += 256) h[i] = 0;
    __syncthreads();
    int stride = gridDim.x * 256;
    for (int e = blockIdx.x * 256 + threadIdx.x; e < etot; e += stride){
        int dst = (e < n_edges) ? ei[n_edges + e] : (e - n_edges);
        atomicAdd(&h[dst >> NODE_SHIFT], 1);
    }
    __syncthreads();
    for (int i = threadIdx.x; i < nbin; i += 256)
        if (h[i]) atomicAdd(&binCnt[i], h[i]);
}

// parallel 256-wide LDS scan
__global__ __launch_bounds__(256) void kb_scan(const int* __restrict__ binCnt,
                        int* __restrict__ binStart,
                        int* __restrict__ binCursor, int nbin,
                        int* __restrict__ rowptr, int n_nodes, int etot){
    __shared__ int s[MAXBIN];
    int t = threadIdx.x;
    int v = (t < nbin) ? binCnt[t] : 0;
    s[t] = v;
    __syncthreads();
    #pragma unroll
    for (int off = 1; off < MAXBIN; off <<= 1){
        int x = (t >= off) ? s[t - off] : 0;
        __syncthreads();
        s[t] += x;
        __syncthreads();
    }
    int excl = s[t] - v;
    if (t < nbin){
        binStart[t]  = excl;
        binCursor[t] = excl;
    }
    if (t == 0){
        binStart[nbin]  = s[MAXBIN - 1];
        rowptr[n_nodes] = etot;
    }
}

__global__ __launch_bounds__(256) void kb_scatter(const int* __restrict__ ei,
                                                  int* __restrict__ binCursor,
                                                  unsigned* __restrict__ staged,
                                                  int n_edges, int etot, int nbin){
    __shared__ int cnt[MAXBIN];
    __shared__ int base[MAXBIN];
    int e0 = blockIdx.x * 4096;
    for (int i = threadIdx.x; i < nbin; i += 256) cnt[i] = 0;
    __syncthreads();
    #pragma unroll 4
    for (int r = 0; r < 16; r++){
        int e = e0 + r * 256 + threadIdx.x;
        if (e < etot){
            int dst = (e < n_edges) ? ei[n_edges + e] : (e - n_edges);
            atomicAdd(&cnt[dst >> NODE_SHIFT], 1);
        }
    }
    __syncthreads();
    for (int i = threadIdx.x; i < nbin; i += 256){
        base[i] = cnt[i] ? atomicAdd(&binCursor[i], cnt[i]) : 0;
        cnt[i] = 0;
    }
    __syncthreads();
    #pragma unroll 4
    for (int r = 0; r < 16; r++){
        int e = e0 + r * 256 + threadIdx.x;
        if (e < etot){
            int src, dst;
            if (e < n_edges){ src = ei[e]; dst = ei[n_edges + e]; }
            else            { src = dst = e - n_edges; }
            int b = dst >> NODE_SHIFT;
            int p = base[b] + atomicAdd(&cnt[b], 1);
            staged[p] = ((unsigned)(dst & (BIN_NODES - 1)) << 17) | (unsigned)src;
        }
    }
}

__global__ __launch_bounds__(512) void kb_final(const unsigned* __restrict__ staged,
                                                const int* __restrict__ binStart,
                                                int* __restrict__ rowptr,
                                                int* __restrict__ eidx, int n_nodes){
    __shared__ int deg[BIN_NODES];
    __shared__ int cur[BIN_NODES];
    int b = blockIdx.x;
    int nbase = b << NODE_SHIFT;
    int s0 = binStart[b], s1 = binStart[b + 1];
    deg[threadIdx.x] = 0;
    __syncthreads();
    for (int i = s0 + threadIdx.x; i < s1; i += 512)
        atomicAdd(&deg[staged[i] >> 17], 1);
    __syncthreads();
    int v = deg[threadIdx.x];
    cur[threadIdx.x] = v;
    __syncthreads();
    for (int off = 1; off < BIN_NODES; off <<= 1){
        int t = (threadIdx.x >= off) ? cur[threadIdx.x - off] : 0;
        __syncthreads();
        cur[threadIdx.x] += t;
        __syncthreads();
    }
    int excl = cur[threadIdx.x] - v;           // exclusive prefix within bin
    int node = nbase + threadIdx.x;
    if (node < n_nodes) rowptr[node] = s0 + excl;
    cur[threadIdx.x] = s0 + excl;              // becomes cursor
    __syncthreads();
    for (int i = s0 + threadIdx.x; i < s1; i += 512){
        unsigned pr = staged[i];
        int p = atomicAdd(&cur[pr >> 17], 1);
        eidx[p] = (int)(pr & 0x1FFFFu);
    }
}

// ---------------- weight prep: f16 W, k-packed B' layout ----------------
// B[k][j] = W[j][k].  B'[kb][j][kk], kb=k>>3, kk=k&7 (f16 bits in ushort).

__global__ void k_prepw(const float* __restrict__ W1, const float* __restrict__ W2,
                        const float* __restrict__ W3, unsigned short* __restrict__ Bp){
    int t = blockIdx.x * 256 + threadIdx.x;          // 0..49151
    if (t >= 49152) return;
    int w = t >> 14;
    int r = t & 16383;
    int k = r >> 7, j = r & 127;
    const float* W = (w == 0) ? W1 : (w == 1) ? W2 : W3;
    float val = W[j * 128 + k];
    int idx = (k >> 3) * 1024 + j * 8 + (k & 7);
    Bp[w * 16384 + idx] = __half_as_ushort(__float2half_rn(val));
}

// ---------------- f16 MFMA GEMM + fused attention coefficients ----------------

template<int FP32SRC>
__global__ __launch_bounds__(256, 4) void k_mgemm(
        const float* __restrict__ Xf, const unsigned short* __restrict__ Xh,
        const unsigned short* __restrict__ Bp,
        const float* __restrict__ aw_s, const float* __restrict__ aw_d,
        unsigned short* __restrict__ Hh,
        float* __restrict__ asrc, float* __restrict__ adst, int n_rows){
    __shared__ unsigned short Bs[16384];         // 32 KB: whole B panel, f16
    int lane = threadIdx.x & 63;
    int wv   = threadIdx.x >> 6;
    int li = lane & 15, quad = lane >> 4;
    int r0 = blockIdx.x * 128 + wv * 32;

    int row0 = r0 + li;
    int row1 = r0 + 16 + li;
    int rc0 = row0 < n_rows ? row0 : 0;
    int rc1 = row1 < n_rows ? row1 : 0;

    // hoist all A fragments (independent of LDS staging)
    v8h a0[4], a1[4];
    #pragma unroll
    for (int ks = 0; ks < 4; ks++){
        int koff = ks * 32 + quad * 8;
        if (FP32SRC){
            float f0[8], f1[8];
            *(float4*)&f0[0] = *(const float4*)(Xf + (size_t)rc0 * 128 + koff);
            *(float4*)&f0[4] = *(const float4*)(Xf + (size_t)rc0 * 128 + koff + 4);
            *(float4*)&f1[0] = *(const float4*)(Xf + (size_t)rc1 * 128 + koff);
            *(float4*)&f1[4] = *(const float4*)(Xf + (size_t)rc1 * 128 + koff + 4);
            #pragma unroll
            for (int i = 0; i < 8; i++){
                a0[ks][i] = (_Float16)f0[i];
                a1[ks][i] = (_Float16)f1[i];
            }
        } else {
            a0[ks] = *(const v8h*)(Xh + (size_t)rc0 * 128 + koff);
            a1[ks] = *(const v8h*)(Xh + (size_t)rc1 * 128 + koff);
        }
    }

    // stage whole B panel: 2048 float4, 8 per thread
    #pragma unroll
    for (int i = 0; i < 8; i++){
        int idx = threadIdx.x + i * 256;
        ((float4*)Bs)[idx] = ((const float4*)Bp)[idx];
    }
    __syncthreads();

    v4f acc[2][8];
    #pragma unroll
    for (int m = 0; m < 2; m++)
        #pragma unroll
        for (int t = 0; t < 8; t++)
            acc[m][t] = (v4f){0.f, 0.f, 0.f, 0.f};

    #pragma unroll
    for (int ks = 0; ks < 4; ks++){
        #pragma unroll
        for (int t = 0; t < 8; t++){
            int bo = (ks * 4 + quad) * 1024 + (t * 16 + li) * 8;
            v8h b = *(const v8h*)(Bs + bo);
            acc[0][t] = __builtin_amdgcn_mfma_f32_16x16x32_f16(a0[ks], b, acc[0][t], 0, 0, 0);
            acc[1][t] = __builtin_amdgcn_mfma_f32_16x16x32_f16(a1[ks], b, acc[1][t], 0, 0, 0);
        }
    }

    // epilogue 1: fp16 mirror
    #pragma unroll
    for (int m = 0; m < 2; m++){
        #pragma unroll
        for (int t = 0; t < 8; t++){
            #pragma unroll
            for (int r = 0; r < 4; r++){
                float v  = acc[m][t][r];
                float vo = __shfl_xor(v, 1);
                if (!(li & 1)){
                    int row = r0 + m * 16 + quad * 4 + r;
                    if (row < n_rows)
                        *(unsigned*)(Hh + (size_t)row * 128 + t * 16 + li) = f2h2(v, vo);
                }
            }
        }
    }

    // epilogue 2: fused attention coefficients (fp32)
    float as8[8], ad8[8];
    #pragma unroll
    for (int t = 0; t < 8; t++){
        as8[t] = aw_s[t * 16 + li];
        ad8[t] = aw_d[t * 16 + li];
    }
    #pragma unroll
    for (int m = 0; m < 2; m++){
        #pragma unroll
        for (int r = 0; r < 4; r++){
            float sp[4], dp[4];
            #pragma unroll
            for (int h = 0; h < 4; h++){
                sp[h] = acc[m][2*h][r] * as8[2*h] + acc[m][2*h+1][r] * as8[2*h+1];
                dp[h] = acc[m][2*h][r] * ad8[2*h] + acc[m][2*h+1][r] * ad8[2*h+1];
            }
            #pragma unroll
            for (int off = 1; off < 16; off <<= 1){
                #pragma unroll
                for (int h = 0; h < 4; h++){
                    sp[h] += __shfl_xor(sp[h], off);
                    dp[h] += __shfl_xor(dp[h], off);
                }
            }
            if (li == 0){
                int row = r0 + m * 16 + quad * 4 + r;
                if (row < n_rows){
                    ((float4*)asrc)[row] = make_float4(sp[0], sp[1], sp[2], sp[3]);
                    ((float4*)adst)[row] = make_float4(dp[0], dp[1], dp[2], dp[3]);
                }
            }
        }
    }
}

// ---------------- fused softmax + aggregation, TWO nodes per wave ----------------
// R3 x4-gather layout per node: lane l = 16g+m; slot t covers edges 4t..4t+3;
// lane-chunk m owns feature pairs 4m..4m+3. Two adjacent nodes (A,B) per wave
// give two independent gather chains -> 2x memory-level parallelism without
// scheduler pinning (R4/R5 lesson: independent work, not ordering constraints).
// MEAN=1: linear readout in-register, one plain 4B store per node (no atomics,
// R4-R6 lesson: memory-side atomic retire cost ~33 us/dispatch).

__device__ __forceinline__ void cons4(uint4 hv, float w, float* acc){
    unsigned u[4] = {hv.x, hv.y, hv.z, hv.w};
    #pragma unroll
    for (int q = 0; q < 4; q++){
        float2 f = h2f2(u[q]);
        acc[2*q]   = fmaf(w, f.x, acc[2*q]);
        acc[2*q+1] = fmaf(w, f.y, acc[2*q+1]);
    }
}

__device__ __forceinline__ float head_sel(int eh, float4 a){
    return eh == 0 ? a.x : eh == 1 ? a.y : eh == 2 ? a.z : a.w;
}

template<int MEAN>
__global__ __launch_bounds__(256, 8) void k_aggr(
        const unsigned* __restrict__ Hh,
        const float* __restrict__ asrc, const float* __restrict__ adst,
        const int* __restrict__ rowptr, const int* __restrict__ eidx,
        const float* __restrict__ bias,
        unsigned short* __restrict__ O,
        const float* __restrict__ lw, const float* __restrict__ lb,
        float* __restrict__ yout, int n_nodes){
    int lane = threadIdx.x & 63;
    int wid  = threadIdx.x >> 6;
    int nA = __builtin_amdgcn_readfirstlane(blockIdx.x * 8 + wid * 2);
    if (nA >= n_nodes) return;
    int nB = nA + 1;
    int hasB = (nB < n_nodes);

    int rowA = __builtin_amdgcn_readfirstlane(rowptr[nA]);
    int degA = __builtin_amdgcn_readfirstlane(rowptr[nA + 1]) - rowA;
    int rowB = 0, degB = 0;
    if (hasB){
        rowB = __builtin_amdgcn_readfirstlane(rowptr[nB]);
        degB = __builtin_amdgcn_readfirstlane(rowptr[nB + 1]) - rowB;
    }
    const int* epA = eidx + rowA;
    const int* epB = eidx + rowB;

    int l  = lane;
    int eh = l & 3;                        // weight-phase head
    int ej = l >> 2;                       // weight-phase edge slot (0..15)
    int m  = l & 15;                       // 16B chunk within row
    int wb = l & 60;                       // bpermute base: addr_t = ((t&3)<<6) + wb
    int hb = l & 12;                       // den bpermute addr (head m>>2)

    float adwA = head_sel(eh, ((const float4*)adst)[nA]);
    float adwB = 0.f;
    if (hasB) adwB = head_sel(eh, ((const float4*)adst)[nB]);

    const uint4* H4 = (const uint4*)Hh;
    float accA[8], accB[8];
    #pragma unroll
    for (int q = 0; q < 8; q++){ accA[q] = 0.f; accB[q] = 0.f; }
    float denpA = 0.f, denpB = 0.f;

    int iA = 0, iB = 0;
    while (iA < degA || iB < degB){
        int remA = degA - iA; remA = remA < 0 ? 0 : (remA > 32 ? 32 : remA);
        int remB = degB - iB; remB = remB < 0 ? 0 : (remB > 32 ? 32 : remB);

        // ---- weight phase A ----
        int sv0A = 0, sv1A = 0, w0iA = 0, w1iA = 0;
        if (remA > 0){
            int last = iA + remA - 1;
            int j0 = iA + ej;
            sv0A = epA[j0 < last ? j0 : last];
            float t0 = asrc[(size_t)(unsigned)sv0A * 4u + (unsigned)eh] + adwA;
            float w0f = __expf(fmaxf(t0, NEG * t0));
            float w0 = (ej < remA) ? w0f : 0.f;
            denpA += w0;
            w0iA = __float_as_int(w0);
            sv1A = sv0A;
            if (remA > 16){
                int j1 = iA + 16 + ej;
                sv1A = epA[j1 < last ? j1 : last];
                float t1 = asrc[(size_t)(unsigned)sv1A * 4u + (unsigned)eh] + adwA;
                float w1f = __expf(fmaxf(t1, NEG * t1));
                float w1 = (16 + ej < remA) ? w1f : 0.f;
                denpA += w1;
                w1iA = __float_as_int(w1);
            }
        }
        // ---- weight phase B ----
        int sv0B = 0, sv1B = 0, w0iB = 0, w1iB = 0;
        if (remB > 0){
            int last = iB + remB - 1;
            int j0 = iB + ej;
            sv0B = epB[j0 < last ? j0 : last];
            float t0 = asrc[(size_t)(unsigned)sv0B * 4u + (unsigned)eh] + adwB;
            float w0f = __expf(fmaxf(t0, NEG * t0));
            float w0 = (ej < remB) ? w0f : 0.f;
            denpB += w0;
            w0iB = __float_as_int(w0);
            sv1B = sv0B;
            if (remB > 16){
                int j1 = iB + 16 + ej;
                sv1B = epB[j1 < last ? j1 : last];
                float t1 = asrc[(size_t)(unsigned)sv1B * 4u + (unsigned)eh] + adwB;
                float w1f = __expf(fmaxf(t1, NEG * t1));
                float w1 = (16 + ej < remB) ? w1f : 0.f;
                denpB += w1;
                w1iB = __float_as_int(w1);
            }
        }

        uint4 hA0, hA1, hA2, hA3, hA4, hA5, hA6, hA7;
        uint4 hB0, hB1, hB2, hB3, hB4, hB5, hB6, hB7;
#define GLOADX(hv, t, svx, rem) \
        if ((t) * 4 < rem){ \
            int s_ = __builtin_amdgcn_ds_bpermute((((t) & 3) << 6) + wb, svx); \
            hv = H4[(unsigned)s_ * 16u + (unsigned)m]; \
        }
#define GCONSX(hv, t, wxi, rem, accv) \
        if ((t) * 4 < rem){ \
            float wt_ = __int_as_float(__builtin_amdgcn_ds_bpermute((((t) & 3) << 6) + wb, wxi)); \
            cons4(hv, wt_, accv); \
        }
        GLOADX(hA0, 0, sv0A, remA) GLOADX(hA1, 1, sv0A, remA)
        GLOADX(hA2, 2, sv0A, remA) GLOADX(hA3, 3, sv0A, remA)
        GLOADX(hA4, 4, sv1A, remA) GLOADX(hA5, 5, sv1A, remA)
        GLOADX(hA6, 6, sv1A, remA) GLOADX(hA7, 7, sv1A, remA)
        GLOADX(hB0, 0, sv0B, remB) GLOADX(hB1, 1, sv0B, remB)
        GLOADX(hB2, 2, sv0B, remB) GLOADX(hB3, 3, sv0B, remB)
        GLOADX(hB4, 4, sv1B, remB) GLOADX(hB5, 5, sv1B, remB)
        GLOADX(hB6, 6, sv1B, remB) GLOADX(hB7, 7, sv1B, remB)
        GCONSX(hA0, 0, w0iA, remA, accA) GCONSX(hA1, 1, w0iA, remA, accA)
        GCONSX(hA2, 2, w0iA, remA, accA) GCONSX(hA3, 3, w0iA, remA, accA)
        GCONSX(hA4, 4, w1iA, remA, accA) GCONSX(hA5, 5, w1iA, remA, accA)
        GCONSX(hA6, 6, w1iA, remA, accA) GCONSX(hA7, 7, w1iA, remA, accA)
        GCONSX(hB0, 0, w0iB, remB, accB) GCONSX(hB1, 1, w0iB, remB, accB)
        GCONSX(hB2, 2, w0iB, remB, accB) GCONSX(hB3, 3, w0iB, remB, accB)
        GCONSX(hB4, 4, w1iB, remB, accB) GCONSX(hB5, 5, w1iB, remB, accB)
        GCONSX(hB6, 6, w1iB, remB, accB) GCONSX(hB7, 7, w1iB, remB, accB)
#undef GLOADX
#undef GCONSX
        iA += remA; iB += remB;
    }

    // ---- per-node reductions & epilogues ----
    #pragma unroll
    for (int q = 0; q < 8; q++){
        accA[q] += __shfl_xor(accA[q], 16);
        accA[q] += __shfl_xor(accA[q], 32);
        accB[q] += __shfl_xor(accB[q], 16);
        accB[q] += __shfl_xor(accB[q], 32);
    }
    denpA += __shfl_xor(denpA, 4);  denpA += __shfl_xor(denpA, 8);
    denpA += __shfl_xor(denpA, 16); denpA += __shfl_xor(denpA, 32);
    denpB += __shfl_xor(denpB, 4);  denpB += __shfl_xor(denpB, 8);
    denpB += __shfl_xor(denpB, 16); denpB += __shfl_xor(denpB, 32);
    float rdhA = 1.f / __int_as_float(__builtin_amdgcn_ds_bpermute(hb, __float_as_int(denpA)));
    float rdhB = 1.f / __int_as_float(__builtin_amdgcn_ds_bpermute(hb, __float_as_int(denpB)));

    if (!MEAN){
        if (l < 16){                       // g == 0 lanes write features 8m..8m+7
            float4 b0 = *(const float4*)(bias + m * 8);
            float4 b1 = *(const float4*)(bias + m * 8 + 4);
            {
                uint4 ov;
                ov.x = f2h2(elu_f(accA[0] * rdhA + b0.x), elu_f(accA[1] * rdhA + b0.y));
                ov.y = f2h2(elu_f(accA[2] * rdhA + b0.z), elu_f(accA[3] * rdhA + b0.w));
                ov.z = f2h2(elu_f(accA[4] * rdhA + b1.x), elu_f(accA[5] * rdhA + b1.y));
                ov.w = f2h2(elu_f(accA[6] * rdhA + b1.z), elu_f(accA[7] * rdhA + b1.w));
                *(uint4*)(O + (size_t)nA * 128 + m * 8) = ov;
            }
            if (hasB){
                uint4 ov;
                ov.x = f2h2(elu_f(accB[0] * rdhB + b0.x), elu_f(accB[1] * rdhB + b0.y));
                ov.y = f2h2(elu_f(accB[2] * rdhB + b0.z), elu_f(accB[3] * rdhB + b0.w));
                ov.z = f2h2(elu_f(accB[4] * rdhB + b1.x), elu_f(accB[5] * rdhB + b1.y));
                ov.w = f2h2(elu_f(accB[6] * rdhB + b1.z), elu_f(accB[7] * rdhB + b1.w));
                *(uint4*)(O + (size_t)nB * 128 + m * 8) = ov;
            }
        }
    } else {
        float vA[8], vB[8];
        #pragma unroll
        for (int q = 0; q < 8; q++){ vA[q] = accA[q] * rdhA; vB[q] = accB[q] * rdhB; }
        #pragma unroll
        for (int q = 0; q < 8; q++){
            vA[q] += __shfl_xor(vA[q], 4); vA[q] += __shfl_xor(vA[q], 8);
            vB[q] += __shfl_xor(vB[q], 4); vB[q] += __shfl_xor(vB[q], 8);
        }
        float partA = 0.f, partB = 0.f;
        if (l < 4){                        // lane holds out-features 8l..8l+7
            float4 w0 = *(const float4*)(lw + l * 8);
            float4 w1 = *(const float4*)(lw + l * 8 + 4);
            partA = elu_f(vA[0] * 0.25f + bias[l*8+0]) * w0.x
                  + elu_f(vA[1] * 0.25f + bias[l*8+1]) * w0.y
                  + elu_f(vA[2] * 0.25f + bias[l*8+2]) * w0.z
                  + elu_f(vA[3] * 0.25f + bias[l*8+3]) * w0.w
                  + elu_f(vA[4] * 0.25f + bias[l*8+4]) * w1.x
                  + elu_f(vA[5] * 0.25f + bias[l*8+5]) * w1.y
                  + elu_f(vA[6] * 0.25f + bias[l*8+6]) * w1.z
                  + elu_f(vA[7] * 0.25f + bias[l*8+7]) * w1.w;
            partB = elu_f(vB[0] * 0.25f + bias[l*8+0]) * w0.x
                  + elu_f(vB[1] * 0.25f + bias[l*8+1]) * w0.y
                  + elu_f(vB[2] * 0.25f + bias[l*8+2]) * w0.z
                  + elu_f(vB[3] * 0.25f + bias[l*8+3]) * w0.w
                  + elu_f(vB[4] * 0.25f + bias[l*8+4]) * w1.x
                  + elu_f(vB[5] * 0.25f + bias[l*8+5]) * w1.y
                  + elu_f(vB[6] * 0.25f + bias[l*8+6]) * w1.z
                  + elu_f(vB[7] * 0.25f + bias[l*8+7]) * w1.w;
        }
        partA += __shfl_xor(partA, 1); partA += __shfl_xor(partA, 2);
        partB += __shfl_xor(partB, 1); partB += __shfl_xor(partB, 2);
        if (l == 0){
            yout[nA] = partA + lb[0];
            if (hasB) yout[nB] = partB + lb[0];
        }
    }
}

// ---------------- readout: pool per-node scalar y over graphs ----------------

__global__ __launch_bounds__(256) void k_readout(const float* __restrict__ y,
                          const int* __restrict__ batch,
                          float* __restrict__ pool, float* __restrict__ cnt,
                          int n_nodes){
    __shared__ float pl[64];
    __shared__ float cl[64];
    if (threadIdx.x < 64){ pl[threadIdx.x] = 0.f; cl[threadIdx.x] = 0.f; }
    __syncthreads();
    int n = blockIdx.x * 256 + threadIdx.x;
    if (n < n_nodes){
        int b = batch[n];
        atomicAdd(&pl[b], y[n]);
        atomicAdd(&cl[b], 1.f);
    }
    __syncthreads();
    if (threadIdx.x < 64 && cl[threadIdx.x] != 0.f){
        atomicAdd(&pool[threadIdx.x], pl[threadIdx.x]);
        atomicAdd(&cnt[threadIdx.x], cl[threadIdx.x]);
    }
}

__global__ void k_final(const float* __restrict__ pool, const float* __restrict__ cnt,
                        float* __restrict__ out){
    int g = threadIdx.x;
    if (g < 64) out[g] = (cnt[g] > 0.f) ? pool[g] / cnt[g] : 0.f;
}

// ---------------- launch ----------------

extern "C" void kernel_launch(void* const* d_in, const int* in_sizes, int n_in,
                              void* d_out, int out_size, void* d_ws, size_t ws_size,
                              hipStream_t stream){
    const float* x   = (const float*)d_in[0];
    const int*   ei  = (const int*)  d_in[1];
    const int*   bat = (const int*)  d_in[2];
    const float* W1  = (const float*)d_in[3];
    const float* a1s = (const float*)d_in[4];
    const float* a1d = (const float*)d_in[5];
    const float* b1  = (const float*)d_in[6];
    const float* W2  = (const float*)d_in[7];
    const float* a2s = (const float*)d_in[8];
    const float* a2d = (const float*)d_in[9];
    const float* b2  = (const float*)d_in[10];
    const float* W3  = (const float*)d_in[11];
    const float* a3s = (const float*)d_in[12];
    const float* a3d = (const float*)d_in[13];
    const float* b3  = (const float*)d_in[14];
    const float* lw  = (const float*)d_in[15];
    const float* lb  = (const float*)d_in[16];
    (void)n_in; (void)out_size; (void)ws_size;

    const int n_nodes = in_sizes[0] / D1;      // 100000
    const int n_edges = in_sizes[1] / 2;       // 1600000
    const int etot    = n_edges + n_nodes;     // 1700000
    const int nbin    = (n_nodes + BIN_NODES - 1) >> NODE_SHIFT;   // 196

    char* p = (char*)d_ws;
    size_t off = 0;
    auto alloc = [&](size_t bytes) -> char* {
        char* r = p + off;
        off = (off + bytes + 511) & ~(size_t)511;
        return r;
    };
    unsigned short* Hh   = (unsigned short*)alloc((size_t)n_nodes * 128 * 2); // 25.6 MB
    unsigned short* Xh   = (unsigned short*)alloc((size_t)n_nodes * 128 * 2); // 25.6 MB
    float*          asrc = (float*)alloc((size_t)n_nodes * 4 * 4);
    float*          adst = (float*)alloc((size_t)n_nodes * 4 * 4);
    unsigned short* Bp   = (unsigned short*)alloc(3 * 16384 * 2);
    int*      rowptr  = (int*)alloc((size_t)(n_nodes + 1) * 4);
    int*      eidx    = (int*)alloc((size_t)etot * 4);
    unsigned* staged  = (unsigned*)alloc((size_t)etot * 4);        // 6.8 MB packed
    int*      binCnt  = (int*)alloc(MAXBIN * 4);
    int*      binStart= (int*)alloc((MAXBIN + 1) * 4);
    int*      binCur  = (int*)alloc(MAXBIN * 4);
    float*    yv      = (float*)alloc((size_t)n_nodes * 4);        // per-node scalar
    float*    pool    = (float*)alloc(64 * 4);
    float*    cnt     = (float*)alloc(64 * 4);

    hipMemsetAsync(binCnt, 0, MAXBIN * 4, stream);
    hipMemsetAsync(pool, 0, 64 * 4, stream);
    hipMemsetAsync(cnt, 0, 64 * 4, stream);

    k_prepw<<<192, 256, 0, stream>>>(W1, W2, W3, Bp);

    int cb = (etot + 4095) / 4096;             // 416 chunks
    kb_hist<<<cb, 256, 0, stream>>>(ei, binCnt, n_edges, etot, nbin);
    kb_scan<<<1, 256, 0, stream>>>(binCnt, binStart, binCur, nbin, rowptr, n_nodes, etot);
    kb_scatter<<<cb, 256, 0, stream>>>(ei, binCur, staged, n_edges, etot, nbin);
    kb_final<<<nbin, 512, 0, stream>>>(staged, binStart, rowptr, eidx, n_nodes);

    int mb = (n_nodes + 127) / 128;
    int rb = (n_nodes + 7) / 8;                // 2 nodes per wave, 4 waves per block

    // layer 1 (fp32 x -> f16 in registers)
    k_mgemm<1><<<mb, 256, 0, stream>>>(x, nullptr, Bp,
                                       a1s, a1d, Hh, asrc, adst, n_nodes);
    k_aggr<0><<<rb, 256, 0, stream>>>((const unsigned*)Hh, asrc, adst, rowptr, eidx,
                                      b1, Xh, nullptr, nullptr, nullptr, n_nodes);
    // layer 2
    k_mgemm<0><<<mb, 256, 0, stream>>>(nullptr, Xh, Bp + 16384,
                                       a2s, a2d, Hh, asrc, adst, n_nodes);
    k_aggr<0><<<rb, 256, 0, stream>>>((const unsigned*)Hh, asrc, adst, rowptr, eidx,
                                      b2, Xh, nullptr, nullptr, nullptr, n_nodes);
    // layer 3 (linear readout in-register, plain y store)
    k_mgemm<0><<<mb, 256, 0, stream>>>(nullptr, Xh, Bp + 32768,
                                       a3s, a3d, Hh, asrc, adst, n_nodes);
    k_aggr<1><<<rb, 256, 0, stream>>>((const unsigned*)Hh, asrc, adst, rowptr, eidx,
                                      b3, nullptr, lw, lb, yv, n_nodes);

    int ob = (n_nodes + 255) / 256;
    k_readout<<<ob, 256, 0, stream>>>(yv, bat, pool, cnt, n_nodes);
    k_final<<<1, 64, 0, stream>>>(pool, cnt, (float*)d_out);
}

// Round 9
// 591.798 us; speedup vs baseline: 1.7188x; 1.7188x over previous
//
#include <hip/hip_runtime.h>
#include <hip/hip_fp16.h>
#include <math.h>

#define D1 128
#define NEG 0.2f
#define NODE_SHIFT 9
#define BIN_NODES 512
#define MAXBIN 256

typedef _Float16 v8h __attribute__((ext_vector_type(8)));
typedef float v4f __attribute__((ext_vector_type(4)));

__device__ __forceinline__ float elu_f(float v){ return v > 0.f ? v : __expf(v) - 1.f; }

__device__ __forceinline__ unsigned f2h2(float a, float b){           // a->low, b->high
    return ((unsigned)__half_as_ushort(__float2half_rn(b)) << 16) |
           (unsigned)__half_as_ushort(__float2half_rn(a));
}
__device__ __forceinline__ float2 h2f2(unsigned u){
    float lo = __half2float(__ushort_as_half((unsigned short)(u & 0xffffu)));
    float hi = __half2float(__ushort_as_half((unsigned short)(u >> 16)));
    return make_float2(lo, hi);
}

// ---------------- binned CSR build ----------------
// staged entry: (dstLow << 17) | src   (src < 2^17, dstLow < 2^9)

__global__ __launch_bounds__(256) void kb_hist(const int* __restrict__ ei,
                                               int* __restrict__ binCnt,
                                               int n_edges, int etot, int nbin){
    __shared__ int h[MAXBIN];
    for (int i = threadIdx.x; i < nbin; i += 256) h[i] = 0;
    __syncthreads();
    int stride = gridDim.x * 256;
    for (int e = blockIdx.x * 256 + threadIdx.x; e < etot; e += stride){
        int dst = (e < n_edges) ? ei[n_edges + e] : (e - n_edges);
        atomicAdd(&h[dst >> NODE_SHIFT], 1);
    }
    __syncthreads();
    for (int i = threadIdx.x; i < nbin; i += 256)
        if (h[i]) atomicAdd(&binCnt[i], h[i]);
}

// parallel 256-wide LDS scan
__global__ __launch_bounds__(256) void kb_scan(const int* __restrict__ binCnt,
                        int* __restrict__ binStart,
                        int* __restrict__ binCursor, int nbin,
                        int* __restrict__ rowptr, int n_nodes, int etot){
    __shared__ int s[MAXBIN];
    int t = threadIdx.x;
    int v = (t < nbin) ? binCnt[t] : 0;
    s[t] = v;
    __syncthreads();
    #pragma unroll
    for (int off = 1; off < MAXBIN; off <<= 1){
        int x = (t >= off) ? s[t - off] : 0;
        __syncthreads();
        s[t] += x;
        __syncthreads();
    }
    int excl = s[t] - v;
    if (t < nbin){
        binStart[t]  = excl;
        binCursor[t] = excl;
    }
    if (t == 0){
        binStart[nbin]  = s[MAXBIN - 1];
        rowptr[n_nodes] = etot;
    }
}

__global__ __launch_bounds__(256) void kb_scatter(const int* __restrict__ ei,
                                                  int* __restrict__ binCursor,
                                                  unsigned* __restrict__ staged,
                                                  int n_edges, int etot, int nbin){
    __shared__ int cnt[MAXBIN];
    __shared__ int base[MAXBIN];
    int e0 = blockIdx.x * 4096;
    for (int i = threadIdx.x; i < nbin; i += 256) cnt[i] = 0;
    __syncthreads();
    #pragma unroll 4
    for (int r = 0; r < 16; r++){
        int e = e0 + r * 256 + threadIdx.x;
        if (e < etot){
            int dst = (e < n_edges) ? ei[n_edges + e] : (e - n_edges);
            atomicAdd(&cnt[dst >> NODE_SHIFT], 1);
        }
    }
    __syncthreads();
    for (int i = threadIdx.x; i < nbin; i += 256){
        base[i] = cnt[i] ? atomicAdd(&binCursor[i], cnt[i]) : 0;
        cnt[i] = 0;
    }
    __syncthreads();
    #pragma unroll 4
    for (int r = 0; r < 16; r++){
        int e = e0 + r * 256 + threadIdx.x;
        if (e < etot){
            int src, dst;
            if (e < n_edges){ src = ei[e]; dst = ei[n_edges + e]; }
            else            { src = dst = e - n_edges; }
            int b = dst >> NODE_SHIFT;
            int p = base[b] + atomicAdd(&cnt[b], 1);
            staged[p] = ((unsigned)(dst & (BIN_NODES - 1)) << 17) | (unsigned)src;
        }
    }
}

__global__ __launch_bounds__(512) void kb_final(const unsigned* __restrict__ staged,
                                                const int* __restrict__ binStart,
                                                int* __restrict__ rowptr,
                                                int* __restrict__ eidx, int n_nodes){
    __shared__ int deg[BIN_NODES];
    __shared__ int cur[BIN_NODES];
    int b = blockIdx.x;
    int nbase = b << NODE_SHIFT;
    int s0 = binStart[b], s1 = binStart[b + 1];
    deg[threadIdx.x] = 0;
    __syncthreads();
    for (int i = s0 + threadIdx.x; i < s1; i += 512)
        atomicAdd(&deg[staged[i] >> 17], 1);
    __syncthreads();
    int v = deg[threadIdx.x];
    cur[threadIdx.x] = v;
    __syncthreads();
    for (int off = 1; off < BIN_NODES; off <<= 1){
        int t = (threadIdx.x >= off) ? cur[threadIdx.x - off] : 0;
        __syncthreads();
        cur[threadIdx.x] += t;
        __syncthreads();
    }
    int excl = cur[threadIdx.x] - v;           // exclusive prefix within bin
    int node = nbase + threadIdx.x;
    if (node < n_nodes) rowptr[node] = s0 + excl;
    cur[threadIdx.x] = s0 + excl;              // becomes cursor
    __syncthreads();
    for (int i = s0 + threadIdx.x; i < s1; i += 512){
        unsigned pr = staged[i];
        int p = atomicAdd(&cur[pr >> 17], 1);
        eidx[p] = (int)(pr & 0x1FFFFu);
    }
}

// ---------------- weight prep: f16 W, k-packed B' layout ----------------
// B[k][j] = W[j][k].  B'[kb][j][kk], kb=k>>3, kk=k&7 (f16 bits in ushort).

__global__ void k_prepw(const float* __restrict__ W1, const float* __restrict__ W2,
                        const float* __restrict__ W3, unsigned short* __restrict__ Bp){
    int t = blockIdx.x * 256 + threadIdx.x;          // 0..49151
    if (t >= 49152) return;
    int w = t >> 14;
    int r = t & 16383;
    int k = r >> 7, j = r & 127;
    const float* W = (w == 0) ? W1 : (w == 1) ? W2 : W3;
    float val = W[j * 128 + k];
    int idx = (k >> 3) * 1024 + j * 8 + (k & 7);
    Bp[w * 16384 + idx] = __half_as_ushort(__float2half_rn(val));
}

// ---------------- f16 MFMA GEMM + fused attention coefficients ----------------

template<int FP32SRC>
__global__ __launch_bounds__(256, 4) void k_mgemm(
        const float* __restrict__ Xf, const unsigned short* __restrict__ Xh,
        const unsigned short* __restrict__ Bp,
        const float* __restrict__ aw_s, const float* __restrict__ aw_d,
        unsigned short* __restrict__ Hh,
        float* __restrict__ asrc, float* __restrict__ adst, int n_rows){
    __shared__ unsigned short Bs[16384];         // 32 KB: whole B panel, f16
    int lane = threadIdx.x & 63;
    int wv   = threadIdx.x >> 6;
    int li = lane & 15, quad = lane >> 4;
    int r0 = blockIdx.x * 128 + wv * 32;

    int row0 = r0 + li;
    int row1 = r0 + 16 + li;
    int rc0 = row0 < n_rows ? row0 : 0;
    int rc1 = row1 < n_rows ? row1 : 0;

    // hoist all A fragments (independent of LDS staging)
    v8h a0[4], a1[4];
    #pragma unroll
    for (int ks = 0; ks < 4; ks++){
        int koff = ks * 32 + quad * 8;
        if (FP32SRC){
            float f0[8], f1[8];
            *(float4*)&f0[0] = *(const float4*)(Xf + (size_t)rc0 * 128 + koff);
            *(float4*)&f0[4] = *(const float4*)(Xf + (size_t)rc0 * 128 + koff + 4);
            *(float4*)&f1[0] = *(const float4*)(Xf + (size_t)rc1 * 128 + koff);
            *(float4*)&f1[4] = *(const float4*)(Xf + (size_t)rc1 * 128 + koff + 4);
            #pragma unroll
            for (int i = 0; i < 8; i++){
                a0[ks][i] = (_Float16)f0[i];
                a1[ks][i] = (_Float16)f1[i];
            }
        } else {
            a0[ks] = *(const v8h*)(Xh + (size_t)rc0 * 128 + koff);
            a1[ks] = *(const v8h*)(Xh + (size_t)rc1 * 128 + koff);
        }
    }

    // stage whole B panel: 2048 float4, 8 per thread
    #pragma unroll
    for (int i = 0; i < 8; i++){
        int idx = threadIdx.x + i * 256;
        ((float4*)Bs)[idx] = ((const float4*)Bp)[idx];
    }
    __syncthreads();

    v4f acc[2][8];
    #pragma unroll
    for (int m = 0; m < 2; m++)
        #pragma unroll
        for (int t = 0; t < 8; t++)
            acc[m][t] = (v4f){0.f, 0.f, 0.f, 0.f};

    #pragma unroll
    for (int ks = 0; ks < 4; ks++){
        #pragma unroll
        for (int t = 0; t < 8; t++){
            int bo = (ks * 4 + quad) * 1024 + (t * 16 + li) * 8;
            v8h b = *(const v8h*)(Bs + bo);
            acc[0][t] = __builtin_amdgcn_mfma_f32_16x16x32_f16(a0[ks], b, acc[0][t], 0, 0, 0);
            acc[1][t] = __builtin_amdgcn_mfma_f32_16x16x32_f16(a1[ks], b, acc[1][t], 0, 0, 0);
        }
    }

    // epilogue 1: fp16 mirror
    #pragma unroll
    for (int m = 0; m < 2; m++){
        #pragma unroll
        for (int t = 0; t < 8; t++){
            #pragma unroll
            for (int r = 0; r < 4; r++){
                float v  = acc[m][t][r];
                float vo = __shfl_xor(v, 1);
                if (!(li & 1)){
                    int row = r0 + m * 16 + quad * 4 + r;
                    if (row < n_rows)
                        *(unsigned*)(Hh + (size_t)row * 128 + t * 16 + li) = f2h2(v, vo);
                }
            }
        }
    }

    // epilogue 2: fused attention coefficients (fp32)
    float as8[8], ad8[8];
    #pragma unroll
    for (int t = 0; t < 8; t++){
        as8[t] = aw_s[t * 16 + li];
        ad8[t] = aw_d[t * 16 + li];
    }
    #pragma unroll
    for (int m = 0; m < 2; m++){
        #pragma unroll
        for (int r = 0; r < 4; r++){
            float sp[4], dp[4];
            #pragma unroll
            for (int h = 0; h < 4; h++){
                sp[h] = acc[m][2*h][r] * as8[2*h] + acc[m][2*h+1][r] * as8[2*h+1];
                dp[h] = acc[m][2*h][r] * ad8[2*h] + acc[m][2*h+1][r] * ad8[2*h+1];
            }
            #pragma unroll
            for (int off = 1; off < 16; off <<= 1){
                #pragma unroll
                for (int h = 0; h < 4; h++){
                    sp[h] += __shfl_xor(sp[h], off);
                    dp[h] += __shfl_xor(dp[h], off);
                }
            }
            if (li == 0){
                int row = r0 + m * 16 + quad * 4 + r;
                if (row < n_rows){
                    ((float4*)asrc)[row] = make_float4(sp[0], sp[1], sp[2], sp[3]);
                    ((float4*)adst)[row] = make_float4(dp[0], dp[1], dp[2], dp[3]);
                }
            }
        }
    }
}

// ---------------- fused softmax + aggregation, TWO nodes per wave ----------------
// R8 structure, but __launch_bounds__(256,4): 128-VGPR budget so all 16 gather
// tiles stay in registers (R8's (256,8)=64-VGPR cap spilled everything to
// scratch: WRITE_SIZE 25->897 MB, dur 76->261 us). Occupancy drops to ~16
// waves/CU; per-wave in-flight lines rise ~2 -> ~8-16. This is the clean MLP
// probe: VGPR_Count ~96-128 validates it; dur ~76 despite that falsifies the
// latency theory and establishes the gather-fill ceiling.

__device__ __forceinline__ void cons4(uint4 hv, float w, float* acc){
    unsigned u[4] = {hv.x, hv.y, hv.z, hv.w};
    #pragma unroll
    for (int q = 0; q < 4; q++){
        float2 f = h2f2(u[q]);
        acc[2*q]   = fmaf(w, f.x, acc[2*q]);
        acc[2*q+1] = fmaf(w, f.y, acc[2*q+1]);
    }
}

__device__ __forceinline__ float head_sel(int eh, float4 a){
    return eh == 0 ? a.x : eh == 1 ? a.y : eh == 2 ? a.z : a.w;
}

template<int MEAN>
__global__ __launch_bounds__(256, 4) void k_aggr(
        const unsigned* __restrict__ Hh,
        const float* __restrict__ asrc, const float* __restrict__ adst,
        const int* __restrict__ rowptr, const int* __restrict__ eidx,
        const float* __restrict__ bias,
        unsigned short* __restrict__ O,
        const float* __restrict__ lw, const float* __restrict__ lb,
        float* __restrict__ yout, int n_nodes){
    int lane = threadIdx.x & 63;
    int wid  = threadIdx.x >> 6;
    int nA = __builtin_amdgcn_readfirstlane(blockIdx.x * 8 + wid * 2);
    if (nA >= n_nodes) return;
    int nB = nA + 1;
    int hasB = (nB < n_nodes);

    int rowA = __builtin_amdgcn_readfirstlane(rowptr[nA]);
    int degA = __builtin_amdgcn_readfirstlane(rowptr[nA + 1]) - rowA;
    int rowB = 0, degB = 0;
    if (hasB){
        rowB = __builtin_amdgcn_readfirstlane(rowptr[nB]);
        degB = __builtin_amdgcn_readfirstlane(rowptr[nB + 1]) - rowB;
    }
    const int* epA = eidx + rowA;
    const int* epB = eidx + rowB;

    int l  = lane;
    int eh = l & 3;                        // weight-phase head
    int ej = l >> 2;                       // weight-phase edge slot (0..15)
    int m  = l & 15;                       // 16B chunk within row
    int wb = l & 60;                       // bpermute base: addr_t = ((t&3)<<6) + wb
    int hb = l & 12;                       // den bpermute addr (head m>>2)

    float adwA = head_sel(eh, ((const float4*)adst)[nA]);
    float adwB = 0.f;
    if (hasB) adwB = head_sel(eh, ((const float4*)adst)[nB]);

    const uint4* H4 = (const uint4*)Hh;
    float accA[8], accB[8];
    #pragma unroll
    for (int q = 0; q < 8; q++){ accA[q] = 0.f; accB[q] = 0.f; }
    float denpA = 0.f, denpB = 0.f;

    int iA = 0, iB = 0;
    while (iA < degA || iB < degB){
        int remA = degA - iA; remA = remA < 0 ? 0 : (remA > 32 ? 32 : remA);
        int remB = degB - iB; remB = remB < 0 ? 0 : (remB > 32 ? 32 : remB);

        // ---- weight phase A ----
        int sv0A = 0, sv1A = 0, w0iA = 0, w1iA = 0;
        if (remA > 0){
            int last = iA + remA - 1;
            int j0 = iA + ej;
            sv0A = epA[j0 < last ? j0 : last];
            float t0 = asrc[(size_t)(unsigned)sv0A * 4u + (unsigned)eh] + adwA;
            float w0f = __expf(fmaxf(t0, NEG * t0));
            float w0 = (ej < remA) ? w0f : 0.f;
            denpA += w0;
            w0iA = __float_as_int(w0);
            sv1A = sv0A;
            if (remA > 16){
                int j1 = iA + 16 + ej;
                sv1A = epA[j1 < last ? j1 : last];
                float t1 = asrc[(size_t)(unsigned)sv1A * 4u + (unsigned)eh] + adwA;
                float w1f = __expf(fmaxf(t1, NEG * t1));
                float w1 = (16 + ej < remA) ? w1f : 0.f;
                denpA += w1;
                w1iA = __float_as_int(w1);
            }
        }
        // ---- weight phase B ----
        int sv0B = 0, sv1B = 0, w0iB = 0, w1iB = 0;
        if (remB > 0){
            int last = iB + remB - 1;
            int j0 = iB + ej;
            sv0B = epB[j0 < last ? j0 : last];
            float t0 = asrc[(size_t)(unsigned)sv0B * 4u + (unsigned)eh] + adwB;
            float w0f = __expf(fmaxf(t0, NEG * t0));
            float w0 = (ej < remB) ? w0f : 0.f;
            denpB += w0;
            w0iB = __float_as_int(w0);
            sv1B = sv0B;
            if (remB > 16){
                int j1 = iB + 16 + ej;
                sv1B = epB[j1 < last ? j1 : last];
                float t1 = asrc[(size_t)(unsigned)sv1B * 4u + (unsigned)eh] + adwB;
                float w1f = __expf(fmaxf(t1, NEG * t1));
                float w1 = (16 + ej < remB) ? w1f : 0.f;
                denpB += w1;
                w1iB = __float_as_int(w1);
            }
        }

        uint4 hA0, hA1, hA2, hA3, hA4, hA5, hA6, hA7;
        uint4 hB0, hB1, hB2, hB3, hB4, hB5, hB6, hB7;
#define GLOADX(hv, t, svx, rem) \
        if ((t) * 4 < rem){ \
            int s_ = __builtin_amdgcn_ds_bpermute((((t) & 3) << 6) + wb, svx); \
            hv = H4[(unsigned)s_ * 16u + (unsigned)m]; \
        }
#define GCONSX(hv, t, wxi, rem, accv) \
        if ((t) * 4 < rem){ \
            float wt_ = __int_as_float(__builtin_amdgcn_ds_bpermute((((t) & 3) << 6) + wb, wxi)); \
            cons4(hv, wt_, accv); \
        }
        GLOADX(hA0, 0, sv0A, remA) GLOADX(hA1, 1, sv0A, remA)
        GLOADX(hA2, 2, sv0A, remA) GLOADX(hA3, 3, sv0A, remA)
        GLOADX(hA4, 4, sv1A, remA) GLOADX(hA5, 5, sv1A, remA)
        GLOADX(hA6, 6, sv1A, remA) GLOADX(hA7, 7, sv1A, remA)
        GLOADX(hB0, 0, sv0B, remB) GLOADX(hB1, 1, sv0B, remB)
        GLOADX(hB2, 2, sv0B, remB) GLOADX(hB3, 3, sv0B, remB)
        GLOADX(hB4, 4, sv1B, remB) GLOADX(hB5, 5, sv1B, remB)
        GLOADX(hB6, 6, sv1B, remB) GLOADX(hB7, 7, sv1B, remB)
        GCONSX(hA0, 0, w0iA, remA, accA) GCONSX(hA1, 1, w0iA, remA, accA)
        GCONSX(hA2, 2, w0iA, remA, accA) GCONSX(hA3, 3, w0iA, remA, accA)
        GCONSX(hA4, 4, w1iA, remA, accA) GCONSX(hA5, 5, w1iA, remA, accA)
        GCONSX(hA6, 6, w1iA, remA, accA) GCONSX(hA7, 7, w1iA, remA, accA)
        GCONSX(hB0, 0, w0iB, remB, accB) GCONSX(hB1, 1, w0iB, remB, accB)
        GCONSX(hB2, 2, w0iB, remB, accB) GCONSX(hB3, 3, w0iB, remB, accB)
        GCONSX(hB4, 4, w1iB, remB, accB) GCONSX(hB5, 5, w1iB, remB, accB)
        GCONSX(hB6, 6, w1iB, remB, accB) GCONSX(hB7, 7, w1iB, remB, accB)
#undef GLOADX
#undef GCONSX
        iA += remA; iB += remB;
    }

    // ---- per-node reductions & epilogues ----
    #pragma unroll
    for (int q = 0; q < 8; q++){
        accA[q] += __shfl_xor(accA[q], 16);
        accA[q] += __shfl_xor(accA[q], 32);
        accB[q] += __shfl_xor(accB[q], 16);
        accB[q] += __shfl_xor(accB[q], 32);
    }
    denpA += __shfl_xor(denpA, 4);  denpA += __shfl_xor(denpA, 8);
    denpA += __shfl_xor(denpA, 16); denpA += __shfl_xor(denpA, 32);
    denpB += __shfl_xor(denpB, 4);  denpB += __shfl_xor(denpB, 8);
    denpB += __shfl_xor(denpB, 16); denpB += __shfl_xor(denpB, 32);
    float rdhA = 1.f / __int_as_float(__builtin_amdgcn_ds_bpermute(hb, __float_as_int(denpA)));
    float rdhB = 1.f / __int_as_float(__builtin_amdgcn_ds_bpermute(hb, __float_as_int(denpB)));

    if (!MEAN){
        if (l < 16){                       // g == 0 lanes write features 8m..8m+7
            float4 b0 = *(const float4*)(bias + m * 8);
            float4 b1 = *(const float4*)(bias + m * 8 + 4);
            {
                uint4 ov;
                ov.x = f2h2(elu_f(accA[0] * rdhA + b0.x), elu_f(accA[1] * rdhA + b0.y));
                ov.y = f2h2(elu_f(accA[2] * rdhA + b0.z), elu_f(accA[3] * rdhA + b0.w));
                ov.z = f2h2(elu_f(accA[4] * rdhA + b1.x), elu_f(accA[5] * rdhA + b1.y));
                ov.w = f2h2(elu_f(accA[6] * rdhA + b1.z), elu_f(accA[7] * rdhA + b1.w));
                *(uint4*)(O + (size_t)nA * 128 + m * 8) = ov;
            }
            if (hasB){
                uint4 ov;
                ov.x = f2h2(elu_f(accB[0] * rdhB + b0.x), elu_f(accB[1] * rdhB + b0.y));
                ov.y = f2h2(elu_f(accB[2] * rdhB + b0.z), elu_f(accB[3] * rdhB + b0.w));
                ov.z = f2h2(elu_f(accB[4] * rdhB + b1.x), elu_f(accB[5] * rdhB + b1.y));
                ov.w = f2h2(elu_f(accB[6] * rdhB + b1.z), elu_f(accB[7] * rdhB + b1.w));
                *(uint4*)(O + (size_t)nB * 128 + m * 8) = ov;
            }
        }
    } else {
        float vA[8], vB[8];
        #pragma unroll
        for (int q = 0; q < 8; q++){ vA[q] = accA[q] * rdhA; vB[q] = accB[q] * rdhB; }
        #pragma unroll
        for (int q = 0; q < 8; q++){
            vA[q] += __shfl_xor(vA[q], 4); vA[q] += __shfl_xor(vA[q], 8);
            vB[q] += __shfl_xor(vB[q], 4); vB[q] += __shfl_xor(vB[q], 8);
        }
        float partA = 0.f, partB = 0.f;
        if (l < 4){                        // lane holds out-features 8l..8l+7
            float4 w0 = *(const float4*)(lw + l * 8);
            float4 w1 = *(const float4*)(lw + l * 8 + 4);
            partA = elu_f(vA[0] * 0.25f + bias[l*8+0]) * w0.x
                  + elu_f(vA[1] * 0.25f + bias[l*8+1]) * w0.y
                  + elu_f(vA[2] * 0.25f + bias[l*8+2]) * w0.z
                  + elu_f(vA[3] * 0.25f + bias[l*8+3]) * w0.w
                  + elu_f(vA[4] * 0.25f + bias[l*8+4]) * w1.x
                  + elu_f(vA[5] * 0.25f + bias[l*8+5]) * w1.y
                  + elu_f(vA[6] * 0.25f + bias[l*8+6]) * w1.z
                  + elu_f(vA[7] * 0.25f + bias[l*8+7]) * w1.w;
            partB = elu_f(vB[0] * 0.25f + bias[l*8+0]) * w0.x
                  + elu_f(vB[1] * 0.25f + bias[l*8+1]) * w0.y
                  + elu_f(vB[2] * 0.25f + bias[l*8+2]) * w0.z
                  + elu_f(vB[3] * 0.25f + bias[l*8+3]) * w0.w
                  + elu_f(vB[4] * 0.25f + bias[l*8+4]) * w1.x
                  + elu_f(vB[5] * 0.25f + bias[l*8+5]) * w1.y
                  + elu_f(vB[6] * 0.25f + bias[l*8+6]) * w1.z
                  + elu_f(vB[7] * 0.25f + bias[l*8+7]) * w1.w;
        }
        partA += __shfl_xor(partA, 1); partA += __shfl_xor(partA, 2);
        partB += __shfl_xor(partB, 1); partB += __shfl_xor(partB, 2);
        if (l == 0){
            yout[nA] = partA + lb[0];
            if (hasB) yout[nB] = partB + lb[0];
        }
    }
}

// ---------------- readout: pool per-node scalar y over graphs ----------------

__global__ __launch_bounds__(256) void k_readout(const float* __restrict__ y,
                          const int* __restrict__ batch,
                          float* __restrict__ pool, float* __restrict__ cnt,
                          int n_nodes){
    __shared__ float pl[64];
    __shared__ float cl[64];
    if (threadIdx.x < 64){ pl[threadIdx.x] = 0.f; cl[threadIdx.x] = 0.f; }
    __syncthreads();
    int n = blockIdx.x * 256 + threadIdx.x;
    if (n < n_nodes){
        int b = batch[n];
        atomicAdd(&pl[b], y[n]);
        atomicAdd(&cl[b], 1.f);
    }
    __syncthreads();
    if (threadIdx.x < 64 && cl[threadIdx.x] != 0.f){
        atomicAdd(&pool[threadIdx.x], pl[threadIdx.x]);
        atomicAdd(&cnt[threadIdx.x], cl[threadIdx.x]);
    }
}

__global__ void k_final(const float* __restrict__ pool, const float* __restrict__ cnt,
                        float* __restrict__ out){
    int g = threadIdx.x;
    if (g < 64) out[g] = (cnt[g] > 0.f) ? pool[g] / cnt[g] : 0.f;
}

// ---------------- launch ----------------

extern "C" void kernel_launch(void* const* d_in, const int* in_sizes, int n_in,
                              void* d_out, int out_size, void* d_ws, size_t ws_size,
                              hipStream_t stream){
    const float* x   = (const float*)d_in[0];
    const int*   ei  = (const int*)  d_in[1];
    const int*   bat = (const int*)  d_in[2];
    const float* W1  = (const float*)d_in[3];
    const float* a1s = (const float*)d_in[4];
    const float* a1d = (const float*)d_in[5];
    const float* b1  = (const float*)d_in[6];
    const float* W2  = (const float*)d_in[7];
    const float* a2s = (const float*)d_in[8];
    const float* a2d = (const float*)d_in[9];
    const float* b2  = (const float*)d_in[10];
    const float* W3  = (const float*)d_in[11];
    const float* a3s = (const float*)d_in[12];
    const float* a3d = (const float*)d_in[13];
    const float* b3  = (const float*)d_in[14];
    const float* lw  = (const float*)d_in[15];
    const float* lb  = (const float*)d_in[16];
    (void)n_in; (void)out_size; (void)ws_size;

    const int n_nodes = in_sizes[0] / D1;      // 100000
    const int n_edges = in_sizes[1] / 2;       // 1600000
    const int etot    = n_edges + n_nodes;     // 1700000
    const int nbin    = (n_nodes + BIN_NODES - 1) >> NODE_SHIFT;   // 196

    char* p = (char*)d_ws;
    size_t off = 0;
    auto alloc = [&](size_t bytes) -> char* {
        char* r = p + off;
        off = (off + bytes + 511) & ~(size_t)511;
        return r;
    };
    unsigned short* Hh   = (unsigned short*)alloc((size_t)n_nodes * 128 * 2); // 25.6 MB
    unsigned short* Xh   = (unsigned short*)alloc((size_t)n_nodes * 128 * 2); // 25.6 MB
    float*          asrc = (float*)alloc((size_t)n_nodes * 4 * 4);
    float*          adst = (float*)alloc((size_t)n_nodes * 4 * 4);
    unsigned short* Bp   = (unsigned short*)alloc(3 * 16384 * 2);
    int*      rowptr  = (int*)alloc((size_t)(n_nodes + 1) * 4);
    int*      eidx    = (int*)alloc((size_t)etot * 4);
    unsigned* staged  = (unsigned*)alloc((size_t)etot * 4);        // 6.8 MB packed
    int*      binCnt  = (int*)alloc(MAXBIN * 4);
    int*      binStart= (int*)alloc((MAXBIN + 1) * 4);
    int*      binCur  = (int*)alloc(MAXBIN * 4);
    float*    yv      = (float*)alloc((size_t)n_nodes * 4);        // per-node scalar
    float*    pool    = (float*)alloc(64 * 4);
    float*    cnt     = (float*)alloc(64 * 4);

    hipMemsetAsync(binCnt, 0, MAXBIN * 4, stream);
    hipMemsetAsync(pool, 0, 64 * 4, stream);
    hipMemsetAsync(cnt, 0, 64 * 4, stream);

    k_prepw<<<192, 256, 0, stream>>>(W1, W2, W3, Bp);

    int cb = (etot + 4095) / 4096;             // 416 chunks
    kb_hist<<<cb, 256, 0, stream>>>(ei, binCnt, n_edges, etot, nbin);
    kb_scan<<<1, 256, 0, stream>>>(binCnt, binStart, binCur, nbin, rowptr, n_nodes, etot);
    kb_scatter<<<cb, 256, 0, stream>>>(ei, binCur, staged, n_edges, etot, nbin);
    kb_final<<<nbin, 512, 0, stream>>>(staged, binStart, rowptr, eidx, n_nodes);

    int mb = (n_nodes + 127) / 128;
    int rb = (n_nodes + 7) / 8;                // 2 nodes per wave, 4 waves per block

    // layer 1 (fp32 x -> f16 in registers)
    k_mgemm<1><<<mb, 256, 0, stream>>>(x, nullptr, Bp,
                                       a1s, a1d, Hh, asrc, adst, n_nodes);
    k_aggr<0><<<rb, 256, 0, stream>>>((const unsigned*)Hh, asrc, adst, rowptr, eidx,
                                      b1, Xh, nullptr, nullptr, nullptr, n_nodes);
    // layer 2
    k_mgemm<0><<<mb, 256, 0, stream>>>(nullptr, Xh, Bp + 16384,
                                       a2s, a2d, Hh, asrc, adst, n_nodes);
    k_aggr<0><<<rb, 256, 0, stream>>>((const unsigned*)Hh, asrc, adst, rowptr, eidx,
                                      b2, Xh, nullptr, nullptr, nullptr, n_nodes);
    // layer 3 (linear readout in-register, plain y store)
    k_mgemm<0><<<mb, 256, 0, stream>>>(nullptr, Xh, Bp + 32768,
                                       a3s, a3d, Hh, asrc, adst, n_nodes);
    k_aggr<1><<<rb, 256, 0, stream>>>((const unsigned*)Hh, asrc, adst, rowptr, eidx,
                                      b3, nullptr, lw, lb, yv, n_nodes);

    int ob = (n_nodes + 255) / 256;
    k_readout<<<ob, 256, 0, stream>>>(yv, bat, pool, cnt, n_nodes);
    k_final<<<1, 64, 0, stream>>>(pool, cnt, (float*)d_out);
}